// Round 1
// baseline (24428.865 us; speedup 1.0000x reference)
//
#include <hip/hip_runtime.h>
#include <stdint.h>

#define TT 16384
#define DH 512
#define KK 128
#define SENT 0xAAAAAAAAu

__device__ __forceinline__ uint32_t agent_load(const uint32_t* p) {
    return __hip_atomic_load(p, __ATOMIC_RELAXED, __HIP_MEMORY_SCOPE_AGENT);
}
__device__ __forceinline__ void agent_store(uint32_t* p, uint32_t v) {
    __hip_atomic_store(p, v, __ATOMIC_RELAXED, __HIP_MEMORY_SCOPE_AGENT);
}

// Persistent pipelined scan: 32 blocks x 256 threads.
// Blocks 0..15: layer 0 (input X, output H0). Blocks 16..31: layer 1 (input H0 polled, output H1).
// Each block owns 32 output columns; each thread holds 64 Wx + 64 Wh weights in VGPRs.
// Sync: data-as-flag. h words are agent-scope atomic stores; readers poll until != 0xAAAAAAAA.
// relu output has sign bit clear => can never equal the sentinel.
__global__ __launch_bounds__(256, 1)
void rnn_scan(const float* __restrict__ X,
              const float* __restrict__ Wx0, const float* __restrict__ Wh0,
              const float* __restrict__ bh0, const float* __restrict__ h00,
              const float* __restrict__ Wx1, const float* __restrict__ Wh1,
              const float* __restrict__ bh1, const float* __restrict__ h01,
              float* __restrict__ H0, float* __restrict__ H1)
{
    const int layer = blockIdx.x >> 4;
    const int slice = blockIdx.x & 15;
    const int tid   = threadIdx.x;
    const int o     = tid & 31;          // output within slice
    const int c     = tid >> 5;          // input chunk 0..7 (64 inputs each)
    const int og    = slice * 32 + o;    // global output column

    const float* Wx = layer ? Wx1 : Wx0;
    const float* Wh = layer ? Wh1 : Wh0;
    const float* bh = layer ? bh1 : bh0;
    const float* h0 = layer ? h01 : h00;
    float* Hout = layer ? H1 : H0;

    // ---- one-time: weights into VGPRs (coalesced across the 32 o-lanes) ----
    float wx[64], wh[64];
    #pragma unroll
    for (int j = 0; j < 64; ++j) {
        int i = c * 64 + j;
        wx[j] = Wx[i * DH + og];
        wh[j] = Wh[i * DH + og];
    }
    const float bias = bh[og];

    __shared__ __align__(16) float hbuf[DH];
    __shared__ __align__(16) float xbuf[DH];
    __shared__ float partials[8 * 33];

    // initial h_prev
    hbuf[tid]       = h0[tid];
    hbuf[tid + 256] = h0[tid + 256];

    const uint32_t* Xpoll = (const uint32_t*)H0;   // layer1 input (polled)
    uint32_t* Hout_u = (uint32_t*)Hout;
    const uint32_t* Hprev_u = (const uint32_t*)Hout;

    // layer0: software-prefetched X row
    float xc0 = 0.f, xc1 = 0.f, xn0 = 0.f, xn1 = 0.f;
    if (layer == 0) {
        xc0 = X[tid];
        xc1 = X[tid + 256];
    }

    for (int t = 0; t < TT; ++t) {
        // ---- stage x_t into LDS (layer0: prefetched regs; layer1: poll H0[t]) ----
        if (layer == 0) {
            xbuf[tid]       = xc0;
            xbuf[tid + 256] = xc1;
            if (t + 1 < TT) {                 // prefetch next row (off critical path)
                xn0 = X[(t + 1) * DH + tid];
                xn1 = X[(t + 1) * DH + tid + 256];
            }
        } else {
            uint32_t v0, v1;
            do { v0 = agent_load(&Xpoll[t * DH + tid]); }       while (v0 == SENT);
            do { v1 = agent_load(&Xpoll[t * DH + tid + 256]); } while (v1 == SENT);
            xbuf[tid]       = __uint_as_float(v0);
            xbuf[tid + 256] = __uint_as_float(v1);
        }

        // issue h_{t-1} poll loads early; check after xacc (poll hidden behind compute)
        uint32_t hv0 = 0, hv1 = 0;
        if (t > 0) {
            hv0 = agent_load(&Hprev_u[(t - 1) * DH + tid]);
            hv1 = agent_load(&Hprev_u[(t - 1) * DH + tid + 256]);
        }

        __syncthreads();   // A: xbuf ready

        // ---- input-projection partial (independent of h) ----
        float acc = 0.f;
        {
            const float4* x4 = (const float4*)&xbuf[c * 64];
            #pragma unroll
            for (int j4 = 0; j4 < 16; ++j4) {
                float4 xv = x4[j4];
                acc += wx[4 * j4 + 0] * xv.x + wx[4 * j4 + 1] * xv.y
                     + wx[4 * j4 + 2] * xv.z + wx[4 * j4 + 3] * xv.w;
            }
        }

        // ---- finish h poll, stage into LDS ----
        if (t > 0) {
            while (hv0 == SENT) hv0 = agent_load(&Hprev_u[(t - 1) * DH + tid]);
            while (hv1 == SENT) hv1 = agent_load(&Hprev_u[(t - 1) * DH + tid + 256]);
            hbuf[tid]       = __uint_as_float(hv0);
            hbuf[tid + 256] = __uint_as_float(hv1);
        }

        __syncthreads();   // B: hbuf ready

        // ---- recurrent partial ----
        {
            const float4* h4 = (const float4*)&hbuf[c * 64];
            #pragma unroll
            for (int j4 = 0; j4 < 16; ++j4) {
                float4 hv = h4[j4];
                acc += wh[4 * j4 + 0] * hv.x + wh[4 * j4 + 1] * hv.y
                     + wh[4 * j4 + 2] * hv.z + wh[4 * j4 + 3] * hv.w;
            }
        }
        partials[c * 33 + o] = acc;

        __syncthreads();   // C: partials ready

        if (tid < 32) {
            float v = bias;
            #pragma unroll
            for (int cc = 0; cc < 8; ++cc) v += partials[cc * 33 + tid];
            v = fmaxf(v, 0.f);
            agent_store(&Hout_u[t * DH + og], __float_as_uint(v));
        }

        if (layer == 0) { xc0 = xn0; xc1 = xn1; }
    }
}

// out[t][k] = dot(H1[t], W_log[k]) + b_log[k].  Block = 8 timesteps x 128 k.
__global__ __launch_bounds__(128, 1)
void logits_kernel(const float* __restrict__ H1, const float* __restrict__ Wl,
                   const float* __restrict__ bl, float* __restrict__ out)
{
    const int t0 = blockIdx.x * 8;
    const int k  = threadIdx.x;

    __shared__ __align__(16) float hs[8 * DH];
    for (int idx = k; idx < 8 * DH / 4; idx += 128)
        ((float4*)hs)[idx] = ((const float4*)&H1[(size_t)t0 * DH])[idx];
    __syncthreads();

    float acc[8];
    const float bk = bl[k];
    #pragma unroll
    for (int r = 0; r < 8; ++r) acc[r] = bk;

    const float4* w4 = (const float4*)&Wl[k * DH];
    for (int j = 0; j < DH / 4; ++j) {
        float4 w = w4[j];
        #pragma unroll
        for (int r = 0; r < 8; ++r) {
            float4 h = ((const float4*)&hs[r * DH])[j];
            acc[r] += w.x * h.x + w.y * h.y + w.z * h.z + w.w * h.w;
        }
    }
    #pragma unroll
    for (int r = 0; r < 8; ++r) out[(size_t)(t0 + r) * KK + k] = acc[r];
}

extern "C" void kernel_launch(void* const* d_in, const int* in_sizes, int n_in,
                              void* d_out, int out_size, void* d_ws, size_t ws_size,
                              hipStream_t stream)
{
    const float* X   = (const float*)d_in[0];
    const float* Wx0 = (const float*)d_in[1];
    const float* Wh0 = (const float*)d_in[2];
    const float* bh0 = (const float*)d_in[3];
    const float* h00 = (const float*)d_in[4];
    const float* Wx1 = (const float*)d_in[5];
    const float* Wh1 = (const float*)d_in[6];
    const float* bh1 = (const float*)d_in[7];
    const float* h01 = (const float*)d_in[8];
    const float* Wl  = (const float*)d_in[9];
    const float* bl  = (const float*)d_in[10];
    float* out = (float*)d_out;

    float* H0 = (float*)d_ws;                       // TT*DH fp32 = 32 MB
    float* H1 = H0 + (size_t)TT * DH;               // TT*DH fp32 = 32 MB

    // Defensive sentinel init (harness also poisons d_ws to 0xAA; this makes it
    // self-contained). hipMemsetAsync is graph-capture legal.
    hipMemsetAsync(d_ws, 0xAA, (size_t)2 * TT * DH * sizeof(float), stream);

    hipLaunchKernelGGL(rnn_scan, dim3(32), dim3(256), 0, stream,
                       X, Wx0, Wh0, bh0, h00, Wx1, Wh1, bh1, h01, H0, H1);
    hipLaunchKernelGGL(logits_kernel, dim3(TT / 8), dim3(128), 0, stream,
                       H1, Wl, bl, out);
}

// Round 2
// 20133.902 us; speedup vs baseline: 1.2133x; 1.2133x over previous
//
#include <hip/hip_runtime.h>
#include <stdint.h>

#define TT 16384
#define DH 512
#define KK 128
#define SENT 0xAAAAAAAAu
#define CROWS 32
#define NCHUNK (TT / CROWS)   // 512
#define NPROJ 56
#define RSLOT 16

// Small cross-block state lives in device globals (ws budget stays at the
// proven 2*TT*DH floats). Re-initialized by init_kernel every launch.
__device__ uint32_t g_ring[2][RSLOT][DH];   // parity-tagged h exchange rings
__device__ uint32_t g_flagXp[2][NCHUNK];    // Xp chunk-ready flags (1 = ready)

static __device__ __forceinline__ uint32_t aload(const uint32_t* p) {
    return __hip_atomic_load(p, __ATOMIC_RELAXED, __HIP_MEMORY_SCOPE_AGENT);
}
static __device__ __forceinline__ void astore(uint32_t* p, uint32_t v) {
    __hip_atomic_store(p, v, __ATOMIC_RELAXED, __HIP_MEMORY_SCOPE_AGENT);
}
static __device__ __forceinline__ float aloadf(const float* p) {
    return __uint_as_float(aload((const uint32_t*)p));
}

__global__ void init_kernel() {
    const int tid = threadIdx.x;
    uint32_t* r = &g_ring[0][0][0];
    for (int i = tid; i < 2 * RSLOT * DH; i += 1024) r[i] = SENT;  // sign bit 1
    uint32_t* f = &g_flagXp[0][0];
    for (int i = tid; i < 2 * NCHUNK; i += 1024) f[i] = SENT;      // != 1
}

// ---------------- projector: 32-row chunk GEMM  dst = src @ W  ----------------
// srcMode 0: plain loads (X, pre-written).  srcMode 1: per-word sentinel poll
// (H0, written live by scan-0; in-place overwrite is safe: sole consumer is us,
// and the chunk is fully staged to LDS before any store).
static __device__ void proj_chunk(const float* __restrict__ W,
                                  const float* __restrict__ src, int srcMode,
                                  float* __restrict__ dst, uint32_t* flag, int t0,
                                  float* inT /* [DH][36] */, float* wt /* [32][516] */)
{
    const int tid = threadIdx.x;
    // stage input chunk transposed: inT[k][row]
    #pragma unroll
    for (int i = 0; i < 16; ++i) {
        int idx = tid + 1024 * i;            // 0..16383
        int row = idx >> 9;
        int col = idx & 511;
        float v;
        if (srcMode == 0) {
            v = src[(size_t)t0 * DH + idx];
        } else {
            const uint32_t* p = (const uint32_t*)src + (size_t)t0 * DH + idx;
            uint32_t u;
            while ((u = aload(p)) == SENT) __builtin_amdgcn_s_sleep(1);
            v = __uint_as_float(u);
        }
        inT[col * 36 + row] = v;
    }
    __syncthreads();

    const int rg = (tid >> 7) & 7;   // row group: rows 4rg..4rg+3
    const int cg = tid & 127;        // col group: cols 4cg..4cg+3
    float acc[4][4] = {{0.f}};

    for (int kt = 0; kt < 16; ++kt) {
        const int k0 = kt * 32;
        #pragma unroll
        for (int i = 0; i < 4; ++i) {                  // stage 32x512 W tile
            int f4 = tid + 1024 * i;                   // 0..4095 float4s
            int wr = f4 >> 7;
            int wc = (f4 & 127) << 2;
            *(float4*)&wt[wr * 516 + wc] =
                *(const float4*)&W[(size_t)(k0 + wr) * DH + wc];
        }
        __syncthreads();
        #pragma unroll 8
        for (int kk = 0; kk < 32; ++kk) {
            float4 a = *(const float4*)&inT[(k0 + kk) * 36 + (rg << 2)];
            float4 w = *(const float4*)&wt[kk * 516 + (cg << 2)];
            acc[0][0] += a.x * w.x; acc[0][1] += a.x * w.y; acc[0][2] += a.x * w.z; acc[0][3] += a.x * w.w;
            acc[1][0] += a.y * w.x; acc[1][1] += a.y * w.y; acc[1][2] += a.y * w.z; acc[1][3] += a.y * w.w;
            acc[2][0] += a.z * w.x; acc[2][1] += a.z * w.y; acc[2][2] += a.z * w.z; acc[2][3] += a.z * w.w;
            acc[3][0] += a.w * w.x; acc[3][1] += a.w * w.y; acc[3][2] += a.w * w.z; acc[3][3] += a.w * w.w;
        }
        __syncthreads();
    }
    #pragma unroll
    for (int i = 0; i < 4; ++i)
        #pragma unroll
        for (int j = 0; j < 4; ++j)
            astore((uint32_t*)&dst[(size_t)(t0 + (rg << 2) + i) * DH + (cg << 2) + j],
                   __float_as_uint(acc[i][j]));
    __threadfence();
    __syncthreads();
    if (tid == 0)
        __hip_atomic_store(flag, 1u, __ATOMIC_RELEASE, __HIP_MEMORY_SCOPE_AGENT);
}

// ---------------- fused persistent kernel ----------------
// grid = 64 x 1024.  Blocks with (b<32 && b%8<2): scan role, layer=b%8, slice=b>>3
// (b%8 swizzle: layer-0 scan blocks land on one XCD if dispatch is round-robin —
// perf heuristic only).  All other blocks: projectors for Xp0/Xp1.
__global__ __launch_bounds__(1024, 1)
void fused(const float* __restrict__ X,
           const float* __restrict__ Wx0, const float* __restrict__ Wh0,
           const float* __restrict__ bh0, const float* __restrict__ h00,
           const float* __restrict__ Wx1, const float* __restrict__ Wh1,
           const float* __restrict__ bh1, const float* __restrict__ h01,
           float* H0r, float* H1r)
{
    __shared__ __align__(16) float s_hbuf[DH];
    __shared__ float s_part[8][128];
    __shared__ __align__(16) float s_inT[DH * 36];    // 73728 B
    __shared__ __align__(16) float s_wt[32 * 516];    // 66048 B

    const int bIdx = blockIdx.x;
    const int m8 = bIdx & 7;
    const int tid = threadIdx.x;

    if (bIdx < 32 && m8 < 2) {
        // ================= scan role =================
        const int L = m8;
        const int b = bIdx >> 3;          // slice 0..3, owns cols [128b,128b+128)
        const int c = tid >> 7;           // input chunk 0..7 (64 inputs)
        const int o = tid & 127;
        const int og = (b << 7) + o;

        const float* Wh  = L ? Wh1 : Wh0;
        const float* bhv = L ? bh1 : bh0;
        const float* h0v = L ? h01 : h00;
        float* Hful      = L ? H1r : H0r;
        const float* Xp  = L ? H0r : H1r;   // Xp1 overlays H0, Xp0 overlays H1
        uint32_t* ring         = &g_ring[L][0][0];
        uint32_t* flagXp       = &g_flagXp[L][0];

        float wh[64];
        #pragma unroll
        for (int j = 0; j < 64; ++j)
            wh[j] = Wh[(size_t)((c << 6) + j) * DH + og];
        const float bias = bhv[og];

        // pollers: 384 threads outside the self range, one remote col each
        const int ptid = (tid + 1024 - ((b << 8) + 256)) & 1023;
        const bool isPoll = ptid < 384;
        const int pcol = (ptid < (b << 7)) ? ptid : ptid + 128;
        const bool isSelf = (c >> 1) == b;
        const bool isRed = tid < 128;     // reducer threads, o == tid

        if (tid < DH) s_hbuf[tid] = h0v[tid];

        float xp_next = 0.f;
        int curCh = -1;
        if (isRed) {
            while (__hip_atomic_load(&flagXp[0], __ATOMIC_ACQUIRE,
                                     __HIP_MEMORY_SCOPE_AGENT) != 1u)
                __builtin_amdgcn_s_sleep(1);
            curCh = 0;
            xp_next = aloadf(&Xp[og]);
        }
        __syncthreads();

        for (int t = 0; t < TT; ++t) {
            if (t > 0 && isPoll) {
                const uint32_t par = (uint32_t)((t - 1) >> 4) & 1u;
                const uint32_t* p = &ring[(((t - 1) & 15) << 9) + pcol];
                uint32_t v;
                do { v = aload(p); } while ((v >> 31) != par);
                s_hbuf[pcol] = __uint_as_float(v & 0x7fffffffu);
            }
            float acc = 0.f;
            if (isSelf | (t == 0)) {       // phase 1: overlaps the round trip
                const float4* h4 = (const float4*)&s_hbuf[c << 6];
                #pragma unroll
                for (int j4 = 0; j4 < 16; ++j4) {
                    float4 hv = h4[j4];
                    acc += wh[4*j4+0]*hv.x + wh[4*j4+1]*hv.y
                         + wh[4*j4+2]*hv.z + wh[4*j4+3]*hv.w;
                }
                s_part[c][o] = acc;
            }
            __syncthreads();               // remote h staged
            if (!(isSelf | (t == 0))) {    // phase 2: remote-dependent FMAs
                const float4* h4 = (const float4*)&s_hbuf[c << 6];
                #pragma unroll
                for (int j4 = 0; j4 < 16; ++j4) {
                    float4 hv = h4[j4];
                    acc += wh[4*j4+0]*hv.x + wh[4*j4+1]*hv.y
                         + wh[4*j4+2]*hv.z + wh[4*j4+3]*hv.w;
                }
                s_part[c][o] = acc;
            }
            __syncthreads();               // partials ready
            if (isRed) {
                float v = bias + xp_next;
                #pragma unroll
                for (int cc = 0; cc < 8; ++cc) v += s_part[cc][o];
                v = fmaxf(v, 0.f);
                const uint32_t hb = __float_as_uint(v);
                // ring store FIRST: other blocks' pollers depend on it
                astore(&ring[((t & 15) << 9) + og],
                       hb | (((uint32_t)(t >> 4) & 1u) << 31));
                astore((uint32_t*)Hful + (size_t)t * DH + og, hb);
                s_hbuf[og] = v;
                if (t + 1 < TT) {          // prefetch next xp (off critical path)
                    const int ch = (t + 1) >> 5;
                    if (ch != curCh) {
                        while (__hip_atomic_load(&flagXp[ch], __ATOMIC_ACQUIRE,
                                                 __HIP_MEMORY_SCOPE_AGENT) != 1u) {}
                        curCh = ch;
                    }
                    xp_next = aloadf(&Xp[(size_t)(t + 1) * DH + og]);
                }
            }
            __syncthreads();               // hbuf self-slice ready for next step
        }
    } else {
        // ================= projector role =================
        const int pi = (bIdx < 32) ? (((bIdx >> 3) * 6) + (m8 - 2))
                                   : (24 + (bIdx - 32));      // 0..55
        for (int cc = pi; cc < NCHUNK; cc += NPROJ) {
            proj_chunk(Wx0, X,   0, H1r /*Xp0*/, &g_flagXp[0][cc], cc * CROWS, s_inT, s_wt);
            proj_chunk(Wx1, H0r, 1, H0r /*Xp1*/, &g_flagXp[1][cc], cc * CROWS, s_inT, s_wt);
        }
    }
}

// out[t][k] = dot(H1[t], W_log[k]) + b_log[k].  Block = 8 timesteps x 128 k.
__global__ __launch_bounds__(128, 1)
void logits_kernel(const float* __restrict__ H1, const float* __restrict__ Wl,
                   const float* __restrict__ bl, float* __restrict__ out)
{
    const int t0 = blockIdx.x * 8;
    const int k = threadIdx.x;

    __shared__ __align__(16) float hs[8 * DH];
    for (int idx = k; idx < 8 * DH / 4; idx += 128)
        ((float4*)hs)[idx] = ((const float4*)&H1[(size_t)t0 * DH])[idx];
    __syncthreads();

    float acc[8];
    const float bk = bl[k];
    #pragma unroll
    for (int r = 0; r < 8; ++r) acc[r] = bk;

    const float4* w4 = (const float4*)&Wl[(size_t)k * DH];
    for (int j = 0; j < DH / 4; ++j) {
        float4 w = w4[j];
        #pragma unroll
        for (int r = 0; r < 8; ++r) {
            float4 h = ((const float4*)&hs[r * DH])[j];
            acc[r] += w.x * h.x + w.y * h.y + w.z * h.z + w.w * h.w;
        }
    }
    #pragma unroll
    for (int r = 0; r < 8; ++r) out[(size_t)(t0 + r) * KK + k] = acc[r];
}

extern "C" void kernel_launch(void* const* d_in, const int* in_sizes, int n_in,
                              void* d_out, int out_size, void* d_ws, size_t ws_size,
                              hipStream_t stream)
{
    const float* X   = (const float*)d_in[0];
    const float* Wx0 = (const float*)d_in[1];
    const float* Wh0 = (const float*)d_in[2];
    const float* bh0 = (const float*)d_in[3];
    const float* h00 = (const float*)d_in[4];
    const float* Wx1 = (const float*)d_in[5];
    const float* Wh1 = (const float*)d_in[6];
    const float* bh1 = (const float*)d_in[7];
    const float* h01 = (const float*)d_in[8];
    const float* Wl  = (const float*)d_in[9];
    const float* bl  = (const float*)d_in[10];
    float* out = (float*)d_out;

    float* H0r = (float*)d_ws;                  // H0, later overlaid by Xp1
    float* H1r = H0r + (size_t)TT * DH;         // Xp0 first, then H1

    // H0 region must start at sentinel (harness poisons d_ws; this is defensive)
    hipMemsetAsync(d_ws, 0xAA, (size_t)TT * DH * sizeof(float), stream);
    hipLaunchKernelGGL(init_kernel, dim3(1), dim3(1024), 0, stream);
    hipLaunchKernelGGL(fused, dim3(64), dim3(1024), 0, stream,
                       X, Wx0, Wh0, bh0, h00, Wx1, Wh1, bh1, h01, H0r, H1r);
    hipLaunchKernelGGL(logits_kernel, dim3(TT / 8), dim3(128), 0, stream,
                       H1r, Wl, bl, out);
}